// Round 1
// baseline (258.579 us; speedup 1.0000x reference)
//
#include <hip/hip_runtime.h>

// CombinedActorModel R7: amortized constants + zero-LDS main loop.
// - Each block handles TPB=16 tiles of 64 elements (1024 elems); grid 1024.
// - The 21 weight fragments (84 VGPRs/lane) are loaded ONCE per block straight
//   from global (L2-hot 21.5 KB) -- no LDS staging, no __syncthreads anywhere.
// - All biases are folded into spare K-slots of the fragments:
//     stage1: k=27 column, B-operand supplies Bs[27]=1 (lane q=3, j=3)
//     stage2/3: sigma-packed slot kc=25 <-> (q=2, j=5); P[5]/Hh[5] forced to 1
//   so every MFMA C-operand is literal zero: the 21 per-tile bias ds_reads and
//   the bias array are gone.
// - Spatial is read per-lane directly from global (8 masked dwords/lane) with a
//   one-tile-ahead ping-pong prefetch (statically indexed buffers).
// - LDS is only a 2.3 KB per-wave scratch to compact the 9-channel output into
//   coalesced float4 stores (same-wave DS ordering, no barrier).

typedef _Float16 half8  __attribute__((ext_vector_type(8)));
typedef float    floatx4 __attribute__((ext_vector_type(4)));

#define NFRAG 21                    // 3 actors * (4 stage1 + 2 stage2 + 1 stage3)
#define FRAG_HALFS (NFRAG * 512)    // 10752 halfs = 21504 B
#define TPB 16                      // 64-elem tiles per block

__global__ __launch_bounds__(256) void prep_frags(
    const float* __restrict__ Wmx, const float* __restrict__ bmx,
    const float* __restrict__ Wnx, const float* __restrict__ bnx,
    const float* __restrict__ Wmy, const float* __restrict__ bmy,
    const float* __restrict__ Wny, const float* __restrict__ bny,
    const float* __restrict__ Wmz, const float* __restrict__ bmz,
    const float* __restrict__ Wnz, const float* __restrict__ bnz,
    const float* __restrict__ Wlin, const float* __restrict__ blin,
    const float* __restrict__ Wout, const float* __restrict__ bout,
    _Float16* __restrict__ frag)
{
    int i = threadIdx.x + blockIdx.x * blockDim.x;
    if (i >= FRAG_HALFS) return;
    int f = i >> 9, rem = i & 511;
    int lane = rem >> 3, j = rem & 7;
    int q = lane >> 4, m = lane & 15;
    int a = f / 7, idx = f % 7;
    float v = 0.f;
    if (idx < 4) {
        // stage1 A-frag: rows = stage1 cols c, k = feature (standard 8q+j);
        // bias folded at k==27 (B operand supplies 1.0 there).
        int c = m + ((idx & 1) ? 16 : 0);
        int k = 8 * q + j;
        bool npart = (idx >= 2);
        if (c < 10) {
            if (!npart) { if (k < 6)             v = Wmx[(a*10 + c)*6 + k];
                          else if (k == 27)      v = bmx[a*10 + c]; }
            else        { if (k >= 6 && k < 9)   v = Wnx[(a*10 + c)*3 + (k-6)];
                          else if (k == 27)      v = bnx[a*10 + c]; }
        } else if (c < 20) {
            if (!npart) { if (k >= 9 && k < 15)  v = Wmy[(a*10 + c-10)*6 + (k-9)];
                          else if (k == 27)      v = bmy[a*10 + c-10]; }
            else        { if (k >= 15 && k < 18) v = Wny[(a*10 + c-10)*3 + (k-15)];
                          else if (k == 27)      v = bny[a*10 + c-10]; }
        } else if (c < 25) {
            if (!npart) { if (k >= 18 && k < 24) v = Wmz[(a*5 + c-20)*6 + (k-18)];
                          else if (k == 27)      v = bmz[a*5 + c-20]; }
            else        { if (k >= 24 && k < 27) v = Wnz[(a*5 + c-20)*3 + (k-24)];
                          else if (k == 27)      v = bnz[a*5 + c-20]; }
        }
    } else if (idx < 6) {
        // stage2 A-frag: rows = o, k permuted by sigma; bias at kc==25
        int o  = m + ((idx == 5) ? 16 : 0);
        int kc = 16 * (j >> 2) + 4 * q + (j & 3);   // sigma(q,j)
        if (o < 25) {
            if (kc < 25)       v = Wlin[(a*25 + o)*25 + kc];
            else if (kc == 25) v = blin[a*25 + o];
        }
    } else {
        // stage3 A-frag: rows = ch, k permuted by sigma; bias at ko==25
        int ko = 16 * (j >> 2) + 4 * q + (j & 3);
        if (m < 10) {
            if (ko < 25)       v = Wout[(a*15 + m)*25 + ko];
            else if (ko == 25) v = bout[a*15 + m];
        }
    }
    frag[(size_t)f * 512 + lane * 8 + j] = (_Float16)v;
}

__global__ __launch_bounds__(256) void actor_mfma(
    const float* __restrict__ spatial,
    const _Float16* __restrict__ frag,
    float* __restrict__ out)
{
    __shared__ float lds_o[4 * 144];   // per-wave output compaction scratch

    const int t = threadIdx.x;
    const int lane = t & 63, w = t >> 6;
    const int q = lane >> 4, e = lane & 15;
    const size_t b0 = (size_t)blockIdx.x * (64 * TPB);

    // ---- weight fragments: straight global->VGPR, once per block (L2-hot)
    half8 F[NFRAG];
    #pragma unroll
    for (int f = 0; f < NFRAG; ++f)
        F[f] = *(const half8*)(frag + (size_t)f * 512 + lane * 8);

    const float* sbase = spatial + (b0 + (size_t)(w * 16 + e)) * 27 + 8 * q;
    float* const ldso = lds_o + w * 144;
    const floatx4 z = {0.f, 0.f, 0.f, 0.f};

    auto loadT = [&](float (&dst)[8], int tt) {
        const float* s_ = sbase + (size_t)tt * (64 * 27);
        #pragma unroll
        for (int j = 0; j < 8; ++j) {
            int k = 8 * q + j;
            float v = (k == 27) ? 1.f : 0.f;   // bias slot; k>27 -> 0
            if (k < 27) v = s_[j];
            dst[j] = v;
        }
    };

    auto tileCompute = [&](const float (&cur)[8], int tt) {
        half8 Bs;
        #pragma unroll
        for (int j = 0; j < 8; ++j) Bs[j] = (_Float16)cur[j];

        floatx4 oacc[3];
        #pragma unroll
        for (int a = 0; a < 3; ++a) {
            const int fb = a * 7;
            // stage1: D[c][e]; tiles 0,1 = m-part, 2,3 = n-part (bias via k=27)
            floatx4 M0 = __builtin_amdgcn_mfma_f32_16x16x32_f16(F[fb+0], Bs, z, 0,0,0);
            floatx4 M1 = __builtin_amdgcn_mfma_f32_16x16x32_f16(F[fb+1], Bs, z, 0,0,0);
            floatx4 N0 = __builtin_amdgcn_mfma_f32_16x16x32_f16(F[fb+2], Bs, z, 0,0,0);
            floatx4 N1 = __builtin_amdgcn_mfma_f32_16x16x32_f16(F[fb+3], Bs, z, 0,0,0);

            // glue: P[e][c] = M*N, sigma-packed; slot kc=25 (q=2,j=5) carries
            // the stage2 bias column -> force 1.0
            half8 P;
            #pragma unroll
            for (int r = 0; r < 4; ++r) {
                P[r]     = (_Float16)(M0[r] * N0[r]);
                P[4 + r] = (_Float16)(M1[r] * N1[r]);
            }
            if (q == 2) P[5] = (_Float16)1.f;

            // stage2: D[o][e] (Wlin frag sigma-packed, bias at kc=25)
            floatx4 H0 = __builtin_amdgcn_mfma_f32_16x16x32_f16(F[fb+4], P, z, 0,0,0);
            floatx4 H1 = __builtin_amdgcn_mfma_f32_16x16x32_f16(F[fb+5], P, z, 0,0,0);

            // softsign -> sigma-packed B operand for stage3; bias column = 1.0
            half8 Hh;
            #pragma unroll
            for (int r = 0; r < 4; ++r) {
                float v0 = H0[r];
                Hh[r]     = (_Float16)(v0 * __builtin_amdgcn_rcpf(1.0f + fabsf(v0)));
                float v1 = H1[r];
                Hh[4 + r] = (_Float16)(v1 * __builtin_amdgcn_rcpf(1.0f + fabsf(v1)));
            }
            if (q == 2) Hh[5] = (_Float16)1.f;

            // stage3: D[ch][e]; lane (e,q) reg r holds ch = 4q+r (gate ch9 @ q=2,r=1)
            oacc[a] = __builtin_amdgcn_mfma_f32_16x16x32_f16(F[fb+6], Hh, z, 0,0,0);
        }

        // ---- epilogue: softmax over actors of ch9, weighted sum of ch0..8
        const int src9 = 32 + e;   // lane (e, q=2); its reg1 = ch9
        float g0 = __shfl(oacc[0][1], src9, 64);
        float g1 = __shfl(oacc[1][1], src9, 64);
        float g2 = __shfl(oacc[2][1], src9, 64);
        float mx = fmaxf(g0, fmaxf(g1, g2));
        float e0 = __expf(g0 - mx);
        float e1 = __expf(g1 - mx);
        float e2 = __expf(g2 - mx);
        float inv = __builtin_amdgcn_rcpf(e0 + e1 + e2);
        e0 *= inv; e1 *= inv; e2 *= inv;

        float res[4];
        #pragma unroll
        for (int r = 0; r < 4; ++r)
            res[r] = oacc[0][r] * e0 + oacc[1][r] * e1 + oacc[2][r] * e2;

        // ---- compact to this wave's scratch, coalesced float4 store
        if (q < 2) {
            #pragma unroll
            for (int r = 0; r < 4; ++r) ldso[e * 9 + 4 * q + r] = res[r];
        } else if (q == 2) {
            ldso[e * 9 + 8] = res[0];
        }
        // same-wave DS ordering: writes retire before the reads below issue
        if (lane < 36) {
            float4 v = *(const float4*)(ldso + lane * 4);
            *(float4*)(out + (b0 + (size_t)tt * 64 + w * 16) * 9 + lane * 4) = v;
        }
    };

    // ---- software-pipelined tile loop: prefetch 1 tile ahead, ping-pong regs
    float sA[8], sB[8];
    loadT(sA, 0);
    for (int tt = 0; tt < TPB; tt += 2) {
        loadT(sB, tt + 1);
        tileCompute(sA, tt);
        if (tt + 2 < TPB) loadT(sA, tt + 2);
        tileCompute(sB, tt + 1);
    }
}

extern "C" void kernel_launch(void* const* d_in, const int* in_sizes, int n_in,
                              void* d_out, int out_size, void* d_ws, size_t ws_size,
                              hipStream_t stream) {
    const float* spatial = (const float*)d_in[0];
    // d_in[1] = car_stats: unused by the model, never read.
    const float* Wmx  = (const float*)d_in[2];
    const float* bmx  = (const float*)d_in[3];
    const float* Wnx  = (const float*)d_in[4];
    const float* bnx  = (const float*)d_in[5];
    const float* Wmy  = (const float*)d_in[6];
    const float* bmy  = (const float*)d_in[7];
    const float* Wny  = (const float*)d_in[8];
    const float* bny  = (const float*)d_in[9];
    const float* Wmz  = (const float*)d_in[10];
    const float* bmz  = (const float*)d_in[11];
    const float* Wnz  = (const float*)d_in[12];
    const float* bnz  = (const float*)d_in[13];
    const float* Wlin = (const float*)d_in[14];
    const float* blin = (const float*)d_in[15];
    const float* Wout = (const float*)d_in[16];
    const float* bout = (const float*)d_in[17];
    float* out = (float*)d_out;

    _Float16* frag = (_Float16*)d_ws;   // 21504 B

    prep_frags<<<dim3(42), dim3(256), 0, stream>>>(
        Wmx, bmx, Wnx, bnx, Wmy, bmy, Wny, bny, Wmz, bmz, Wnz, bnz,
        Wlin, blin, Wout, bout, frag);

    const int nb = in_sizes[0] / 27;           // 1048576, multiple of 64*TPB
    dim3 grid(nb / (64 * TPB));                // 1024 blocks, 4 waves each
    actor_mfma<<<grid, dim3(256), 0, stream>>>(spatial, frag, out);
}